// Round 7
// baseline (339.057 us; speedup 1.0000x reference)
//
#include <hip/hip_runtime.h>
#include <hip/hip_cooperative_groups.h>

namespace cg = cooperative_groups;

// Problem constants (fixed by reference: x is (2, 4, 128, 128, 128) fp32)
#define NBATCH 2
#define NDIM   128
#define NP     (128 * 128 * 128)        // particles per batch = mesh cells (2^21)
#define DIS_NORM 3.072f                  // 6 * 512 / 1000

// Tiling: 16^3 origin tiles; LDS window halo LO=5 below, HI=6 above.
// WIN=27 -> 19683 cells as PACKED u64 pairs along w, 2^-24 fixed point,
// ds_add_u64 deposits (6 atomics/particle). 78.7 KB LDS -> 2 blocks/CU.
#define TS   16
#define LO   5
#define HI   6
#define WIN  (TS + LO + HI)              // 27
#define WIN2 (WIN * WIN)                 // 729
#define WINF (WIN * WIN * WIN)           // 19683
#define SLOT 19684                       // padded cells (even)
#define TPB  8
#define NTILE (TPB * TPB * TPB)          // 512 tiles per batch

#define FXSCALE 16777216.0f              // 2^24
#define FXINV   (1.0f / 16777216.0f)

#define NBLK 512                         // cooperative grid: 2 blocks/CU x 256 CU
#define NTHR 512

// ws layout (floats): [0..4096) partial sums (fused: plane*512+blk;
// fallback: plane*128+blk); [4096..) per-tile windows
#define SUMS_OFF 0
#define WINS_OFF 4096
#define WS_FLOATS ((size_t)WINS_OFF + (size_t)NBATCH * NTILE * SLOT)
#define WS_NEEDED_BYTES (WS_FLOATS * sizeof(float))

// ---------------------------------------------------------------------------
// Shared device helpers
// ---------------------------------------------------------------------------

// Packed pair deposit: cells (b, b+1) get (va, vb) in 2^-24 fixed point.
__device__ __forceinline__ void deposit_pair(unsigned long long* __restrict__ winU,
                                             int b, float va, float vb) {
    const int fa = __float2int_rn(va * FXSCALE);
    const int fb = __float2int_rn(vb * FXSCALE);
    const bool odd = (b & 1);
    const long long packed = (((long long)fb) << 32) + (long long)fa;
    const long long hiOnly = ((long long)fa) << 32;
    atomicAdd(&winU[b >> 1], (unsigned long long)(odd ? hiOnly : packed));
    if (odd) atomicAdd(&winU[(b >> 1) + 1], (unsigned long long)(long long)fb);
}

// Scatter one 16^3 tile (4096 particles) with NTHR threads x 8 particles.
// Assumes win2 is zeroed and __syncthreads() already done by caller.
__device__ __forceinline__ void scatter_tile_body(
        const float* __restrict__ x, float m0, float m1, float m2,
        int n, int t, ulonglong2* __restrict__ win2,
        float* __restrict__ wins, float* __restrict__ out) {
    unsigned long long* winU = (unsigned long long*)win2;
    const int tx = t & 7, ty = (t >> 3) & 7, tz = t >> 6;

    const int i0 = threadIdx.x * 8;
    const int lw0 = i0 & 15;
    const int lh  = (i0 >> 4) & 15;
    const int ld  = i0 >> 8;
    const int gd = tz * TS + ld, gh = ty * TS + lh, gw0 = tx * TS + lw0;
    const size_t prow = ((size_t)gd * NDIM + gh) * NDIM + gw0;

    const float4* x4 = (const float4*)(x + (size_t)n * 4 * NP);
    const size_t q = prow >> 2;
    const size_t s4 = NP / 4;
    float4 a0 = x4[0 * s4 + q], a1 = x4[0 * s4 + q + 1];
    float4 b0 = x4[1 * s4 + q], b1 = x4[1 * s4 + q + 1];
    float4 c0 = x4[2 * s4 + q], c1 = x4[2 * s4 + q + 1];
    float4 e0 = x4[3 * s4 + q], e1 = x4[3 * s4 + q + 1];
    const float D0[8] = {a0.x, a0.y, a0.z, a0.w, a1.x, a1.y, a1.z, a1.w};
    const float D1[8] = {b0.x, b0.y, b0.z, b0.w, b1.x, b1.y, b1.z, b1.w};
    const float D2[8] = {c0.x, c0.y, c0.z, c0.w, c1.x, c1.y, c1.z, c1.w};
    const float VV[8] = {e0.x, e0.y, e0.z, e0.w, e1.x, e1.y, e1.z, e1.w};

    const int od = tz * TS - LO, oh = ty * TS - LO, ow = tx * TS - LO;
    float* sp = out + (size_t)n * NP;

    #pragma unroll
    for (int k = 0; k < 8; ++k) {
        const float pd = (D0[k] - m0) * DIS_NORM + (float)gd + 0.5f;
        const float ph = (D1[k] - m1) * DIS_NORM + (float)gh + 0.5f;
        const float pw = (D2[k] - m2) * DIS_NORM + (float)(gw0 + k) + 0.5f;
        const float v = VV[k];

        const float fd = floorf(pd), fh = floorf(ph), fw = floorf(pw);
        const int id = (int)fd, ih = (int)fh, iw = (int)fw;
        const float rd = pd - fd, rh = ph - fh, rw = pw - fw;

        const int wd = id - od, wh = ih - oh, ww = iw - ow;
        if ((unsigned)wd <= WIN - 2 && (unsigned)wh <= WIN - 2 &&
            (unsigned)ww <= WIN - 2) {
            const int b00 = (wd * WIN + wh) * WIN + ww;
            const float sd0 = v * (1.0f - rd), sd1 = v * rd;
            const float h0 = 1.0f - rh, h1 = rh;
            const float q0 = 1.0f - rw, q1 = rw;
            deposit_pair(winU, b00,              sd0 * h0 * q0, sd0 * h0 * q1);
            deposit_pair(winU, b00 + WIN,        sd0 * h1 * q0, sd0 * h1 * q1);
            deposit_pair(winU, b00 + WIN2,       sd1 * h0 * q0, sd1 * h0 * q1);
            deposit_pair(winU, b00 + WIN2 + WIN, sd1 * h1 * q0, sd1 * h1 * q1);
        } else {
            const float wd2[2]  = {1.0f - rd, rd};
            const float wh2[2]  = {1.0f - rh, rh};
            const float ww2[2]  = {1.0f - rw, rw};
            #pragma unroll
            for (int dd = 0; dd < 2; ++dd) {
                const int td = id + dd, wdc = wd + dd;
                const bool dW = (unsigned)wdc < WIN, dM = (unsigned)td < NDIM;
                if (!dM && !dW) continue;
                #pragma unroll
                for (int hh = 0; hh < 2; ++hh) {
                    const int th = ih + hh, whc = wh + hh;
                    const bool hW = (unsigned)whc < WIN, hM = (unsigned)th < NDIM;
                    const float vdh = v * wd2[dd] * wh2[hh];
                    #pragma unroll
                    for (int wi = 0; wi < 2; ++wi) {
                        const int tw = iw + wi, wwc = ww + wi;
                        const bool wW = (unsigned)wwc < WIN, wM = (unsigned)tw < NDIM;
                        const float dep = vdh * ww2[wi];
                        if (dW && hW && wW) {
                            const int cb = (wdc * WIN + whc) * WIN + wwc;
                            const int fx = __float2int_rn(dep * FXSCALE);
                            const long long cv = (cb & 1)
                                ? (((long long)fx) << 32) : (long long)fx;
                            atomicAdd(&winU[cb >> 1], (unsigned long long)cv);
                        } else if (dM && hM && wM) {
                            atomicAdd(sp + ((size_t)td * NDIM + th) * NDIM + tw, dep);
                        }
                    }
                }
            }
        }
    }

    __syncthreads();
    // flush: decode u64 fixed-point pairs -> fp32, coalesced float4 stores
    float4* dst = (float4*)(wins + (size_t)((n << 9) | t) * SLOT);
    for (int i = threadIdx.x; i < SLOT / 4; i += NTHR) {
        const ulonglong2 tv = win2[i];
        const int a0i = (int)(unsigned)(tv.x & 0xffffffffull);
        const int b0i = (int)(tv.x >> 32) + (a0i < 0 ? 1 : 0);
        const int a1i = (int)(unsigned)(tv.y & 0xffffffffull);
        const int b1i = (int)(tv.y >> 32) + (a1i < 0 ? 1 : 0);
        dst[i] = make_float4((float)a0i * FXINV, (float)b0i * FXINV,
                             (float)a1i * FXINV, (float)b1i * FXINV);
    }
}

// Gather helpers
__device__ __forceinline__ int axis_tiles(int c, int* t, int* l) {
    const int r = c & (TS - 1), t0 = c >> 4;
    int cnt = 0;
    t[cnt] = t0; l[cnt] = r + LO; cnt++;
    if (r < HI && t0 > 0)            { t[cnt] = t0 - 1; l[cnt] = r + TS + LO; cnt++; }
    if (r >= TS - LO && t0 < TPB - 1){ t[cnt] = t0 + 1; l[cnt] = r - (TS - LO); cnt++; }
    return cnt;
}

__device__ __forceinline__ void gather_cells(const float* __restrict__ wins,
                                             float* __restrict__ out, size_t i4) {
    const int n = (int)(i4 >> 19);                             // NP/4 = 2^19
    const int p = (int)((i4 & ((NP / 4) - 1)) << 2);
    const int w0 = p & 127, h = (p >> 7) & 127, d = p >> 14;

    float4 acc = ((const float4*)out)[i4];   // spill deposits (zeros elsewhere)
    float* accf = (float*)&acc;

    int tzv[2], lzv[2], tyv[2], lyv[2], txv[2], lxv[2];
    const int nz = axis_tiles(d, tzv, lzv);
    const int ny = axis_tiles(h, tyv, lyv);

    for (int j = 0; j < 4; ++j) {
        const int nx = axis_tiles(w0 + j, txv, lxv);
        float a = 0.f;
        for (int za = 0; za < nz; ++za) {
            for (int ya = 0; ya < ny; ++ya) {
                const int tbase = n * NTILE + tzv[za] * 64 + tyv[ya] * 8;
                const int lbase = (lzv[za] * WIN + lyv[ya]) * WIN;
                for (int xa = 0; xa < nx; ++xa)
                    a += wins[(size_t)(tbase + txv[xa]) * SLOT + lbase + lxv[xa]];
            }
        }
        accf[j] += a;
    }
    ((float4*)out)[i4] = acc;
}

// ---------------------------------------------------------------------------
// Fused cooperative kernel: sums+zero | scatter (2 tiles/block) | gather
// ---------------------------------------------------------------------------
__global__ __launch_bounds__(NTHR, 4) void fused_kernel(const float* __restrict__ x,
                                                        float* __restrict__ ws,
                                                        float* __restrict__ wins,
                                                        float* __restrict__ out) {
    cg::grid_group grid = cg::this_grid();
    const int blk = blockIdx.x;

    __shared__ ulonglong2 win2[SLOT / 4];
    __shared__ float wsum[8];
    __shared__ float meansh[6];

    // ---- Phase 0: zero out + per-block partial sums of 6 planes ----
    {
        float4* o4 = (float4*)out;
        const float4 z = make_float4(0.f, 0.f, 0.f, 0.f);
        for (int i = blk * NTHR + threadIdx.x; i < NBATCH * NP / 4; i += NBLK * NTHR)
            o4[i] = z;
    }
    for (int plane = 0; plane < 6; ++plane) {
        const int n = plane / 3, c = plane % 3;
        const float4* xp = (const float4*)(x + ((size_t)n * 4 + c) * NP);
        float s = 0.0f;
        for (int i = blk * NTHR + threadIdx.x; i < NP / 4; i += NBLK * NTHR) {
            float4 v = xp[i];
            s += (v.x + v.y) + (v.z + v.w);
        }
        #pragma unroll
        for (int off = 32; off > 0; off >>= 1) s += __shfl_down(s, off, 64);
        if ((threadIdx.x & 63) == 0) wsum[threadIdx.x >> 6] = s;
        __syncthreads();
        if (threadIdx.x == 0) {
            float tt = 0.f;
            #pragma unroll
            for (int j = 0; j < 8; ++j) tt += wsum[j];
            ws[SUMS_OFF + plane * NBLK + blk] = tt;
        }
        __syncthreads();
    }
    grid.sync();

    // ---- Phase 1: reduce means (block-local), scatter 2 tiles ----
    {
        const float inv_np = 1.0f / (float)NP;
        for (int plane = 0; plane < 6; ++plane) {
            float s = ws[SUMS_OFF + plane * NBLK + threadIdx.x];  // NTHR == NBLK
            #pragma unroll
            for (int off = 32; off > 0; off >>= 1) s += __shfl_down(s, off, 64);
            if ((threadIdx.x & 63) == 0) wsum[threadIdx.x >> 6] = s;
            __syncthreads();
            if (threadIdx.x == 0) {
                float tt = 0.f;
                #pragma unroll
                for (int j = 0; j < 8; ++j) tt += wsum[j];
                meansh[plane] = tt * inv_np;
            }
            __syncthreads();
        }
    }
    const float mn0 = meansh[0], mn1 = meansh[1], mn2 = meansh[2];
    const float mn3 = meansh[3], mn4 = meansh[4], mn5 = meansh[5];

    #pragma unroll
    for (int nb = 0; nb < NBATCH; ++nb) {
        // zero window
        {
            float4* z4 = (float4*)win2;
            const float4 z = make_float4(0.f, 0.f, 0.f, 0.f);
            for (int i = threadIdx.x; i < SLOT / 4; i += NTHR) z4[i] = z;
        }
        __syncthreads();
        if (nb == 0) scatter_tile_body(x, mn0, mn1, mn2, 0, blk, win2, wins, out);
        else         scatter_tile_body(x, mn3, mn4, mn5, 1, blk, win2, wins, out);
        __syncthreads();
    }
    grid.sync();

    // ---- Phase 2: gather ----
    for (size_t i4 = (size_t)blk * NTHR + threadIdx.x; i4 < (size_t)NBATCH * NP / 4;
         i4 += (size_t)NBLK * NTHR)
        gather_cells(wins, out, i4);
}

// ---------------------------------------------------------------------------
// Fallback 3-kernel path (R6): prep | scatter | gather
// ---------------------------------------------------------------------------
__global__ __launch_bounds__(256) void prep_kernel(const float* __restrict__ x,
                                                   float* __restrict__ ws,
                                                   float* __restrict__ out) {
    const int plane = blockIdx.y;
    if (plane < 6) {
        const int n = plane / 3, c = plane % 3;
        const float4* xp = (const float4*)(x + ((size_t)n * 4 + c) * NP);
        float s = 0.0f;
        for (int i = blockIdx.x * 256 + threadIdx.x; i < NP / 4; i += 128 * 256) {
            float4 v = xp[i];
            s += (v.x + v.y) + (v.z + v.w);
        }
        #pragma unroll
        for (int off = 32; off > 0; off >>= 1) s += __shfl_down(s, off, 64);
        __shared__ float wsum[4];
        if ((threadIdx.x & 63) == 0) wsum[threadIdx.x >> 6] = s;
        __syncthreads();
        if (threadIdx.x == 0)
            ws[SUMS_OFF + plane * 128 + blockIdx.x] =
                (wsum[0] + wsum[1]) + (wsum[2] + wsum[3]);
    } else {
        float4* o4 = (float4*)out;
        const float4 z = make_float4(0.f, 0.f, 0.f, 0.f);
        for (int i = blockIdx.x * 256 + threadIdx.x; i < NBATCH * NP / 4; i += 128 * 256)
            o4[i] = z;
    }
}

__device__ __forceinline__ void load_means128(const float* __restrict__ ws, int n,
                                              float& m0, float& m1, float& m2) {
    float s0 = 0.f, s1 = 0.f, s2 = 0.f;
    const float* p0 = ws + SUMS_OFF + (n * 3 + 0) * 128;
    const float* p1 = ws + SUMS_OFF + (n * 3 + 1) * 128;
    const float* p2 = ws + SUMS_OFF + (n * 3 + 2) * 128;
    #pragma unroll 4
    for (int b = 0; b < 128; ++b) { s0 += p0[b]; s1 += p1[b]; s2 += p2[b]; }
    const float inv_np = 1.0f / (float)NP;
    m0 = s0 * inv_np; m1 = s1 * inv_np; m2 = s2 * inv_np;
}

__global__ __launch_bounds__(NTHR, 4) void scatter_tile_kernel(
        const float* __restrict__ x, const float* __restrict__ ws,
        float* __restrict__ wins, float* __restrict__ out) {
    const int blk = blockIdx.x;              // 0 .. 2*NTILE-1
    const int n = blk >> 9;
    const int t = blk & (NTILE - 1);

    __shared__ ulonglong2 win2[SLOT / 4];
    {
        float4* z4 = (float4*)win2;
        const float4 z = make_float4(0.f, 0.f, 0.f, 0.f);
        for (int i = threadIdx.x; i < SLOT / 4; i += NTHR) z4[i] = z;
    }
    float m0, m1, m2;
    load_means128(ws, n, m0, m1, m2);
    __syncthreads();
    scatter_tile_body(x, m0, m1, m2, n, t, win2, wins, out);
}

__global__ __launch_bounds__(256) void gather_kernel(const float* __restrict__ wins,
                                                     float* __restrict__ out) {
    const size_t i4 = (size_t)blockIdx.x * 256 + threadIdx.x;
    gather_cells(wins, out, i4);
}

__global__ __launch_bounds__(256) void scatter_direct_kernel(const float* __restrict__ x,
                                                             const float* __restrict__ ws,
                                                             float* __restrict__ out) {
    const int lin = blockIdx.x * 256 + threadIdx.x;
    const int n = lin >> 21;
    const int p = lin & (NP - 1);

    float m0, m1, m2;
    load_means128(ws, n, m0, m1, m2);

    const size_t base = (size_t)n * 4 * NP;
    const float d0 = x[base + 0 * (size_t)NP + p];
    const float d1 = x[base + 1 * (size_t)NP + p];
    const float d2 = x[base + 2 * (size_t)NP + p];
    const float v  = x[base + 3 * (size_t)NP + p];

    const int w = p & 127, h = (p >> 7) & 127, d = p >> 14;
    const float pd = (d0 - m0) * DIS_NORM + (float)d + 0.5f;
    const float ph = (d1 - m1) * DIS_NORM + (float)h + 0.5f;
    const float pw = (d2 - m2) * DIS_NORM + (float)w + 0.5f;
    const float fd = floorf(pd), fh = floorf(ph), fw = floorf(pw);
    const int id = (int)fd, ih = (int)fh, iw = (int)fw;
    const float rd = pd - fd, rh = ph - fh, rw = pw - fw;
    const float wd[2] = {1.0f - rd, rd}, wh[2] = {1.0f - rh, rh}, ww[2] = {1.0f - rw, rw};
    float* o = out + (size_t)n * NP;
    #pragma unroll
    for (int dd = 0; dd < 2; ++dd) {
        const int td = id + dd;
        if ((unsigned)td >= (unsigned)NDIM) continue;
        #pragma unroll
        for (int hh = 0; hh < 2; ++hh) {
            const int th = ih + hh;
            if ((unsigned)th >= (unsigned)NDIM) continue;
            const float vdh = v * wd[dd] * wh[hh];
            const int rowbase = (td * NDIM + th) * NDIM;
            #pragma unroll
            for (int wi = 0; wi < 2; ++wi) {
                const int tw = iw + wi;
                if ((unsigned)tw >= (unsigned)NDIM) continue;
                atomicAdd(o + rowbase + tw, vdh * ww[wi]);
            }
        }
    }
}

extern "C" void kernel_launch(void* const* d_in, const int* in_sizes, int n_in,
                              void* d_out, int out_size, void* d_ws, size_t ws_size,
                              hipStream_t stream) {
    const float* x = (const float*)d_in[0];
    float* out = (float*)d_out;
    float* ws = (float*)d_ws;
    float* wins = ws + WINS_OFF;

    if (ws_size >= WS_NEEDED_BYTES) {
        void* args[4] = {(void*)&x, (void*)&ws, (void*)&wins, (void*)&out};
        hipError_t e = hipLaunchCooperativeKernel((const void*)fused_kernel,
                                                  dim3(NBLK), dim3(NTHR),
                                                  args, 0, stream);
        if (e == hipSuccess) return;
        (void)hipGetLastError();   // clear error, fall back to 3-kernel path
        dim3 pgrid(128, 7);
        prep_kernel<<<pgrid, 256, 0, stream>>>(x, ws, out);
        scatter_tile_kernel<<<dim3(NBATCH * NTILE), NTHR, 0, stream>>>(x, ws, wins, out);
        gather_kernel<<<dim3(NBATCH * NP / 4 / 256), 256, 0, stream>>>(wins, out);
    } else {
        dim3 pgrid(128, 7);
        prep_kernel<<<pgrid, 256, 0, stream>>>(x, ws, out);
        scatter_direct_kernel<<<dim3(NBATCH * NP / 256), 256, 0, stream>>>(x, ws, out);
    }
}

// Round 8
// 214.769 us; speedup vs baseline: 1.5787x; 1.5787x over previous
//
#include <hip/hip_runtime.h>

// Problem constants (fixed by reference: x is (2, 4, 128, 128, 128) fp32)
#define NBATCH 2
#define NDIM   128
#define NP     (128 * 128 * 128)        // particles per batch = mesh cells (2^21)
#define DIS_NORM 3.072f                  // 6 * 512 / 1000

// Tiling: 16^3 origin tiles; LDS window halo LO=5 below, HI=6 above.
// WIN=27 -> 19683 cells as PACKED u64 pairs, 2^-24 fixed point, ds_add_u64
// deposits (6 atomics/particle). 78.7 KB LDS -> 2 blocks/CU in scatter.
#define TS   16
#define LO   5
#define HI   6
#define WIN  (TS + LO + HI)              // 27
#define WIN2 (WIN * WIN)                 // 729
#define WINF (WIN * WIN * WIN)           // 19683
#define TPB  8
#define NTILE (TPB * TPB * TPB)          // 512 tiles per batch
#define NTHR 512

#define FXSCALE 16777216.0f              // 2^24
#define FXINV   (1.0f / 16777216.0f)

// Destination-major inbox: each dest tile owns a contiguous slab of 27
// pieces (one per source offset o = src - dest, extents {6,16,5} by o+1),
// piece bases padded to 4 floats. Slab = 19692 -> 19696 floats.
#define SLAB 19696

// ws layout (floats): [0..1024) partial sums; [1024..) per-tile slabs
#define SUMS_OFF 0
#define SLABS_OFF 1024
#define WS_FLOATS ((size_t)SLABS_OFF + (size_t)NBATCH * NTILE * SLAB)
#define WS_NEEDED_BYTES (WS_FLOATS * sizeof(float))

// ---------------------------------------------------------------------------
// Kernel 1: prep. Planes 0..5: per-block partial sums of displacement
// channels. Plane 6: zero d_out (spill deposits land there atomically).
// ---------------------------------------------------------------------------
__global__ __launch_bounds__(256) void prep_kernel(const float* __restrict__ x,
                                                   float* __restrict__ ws,
                                                   float* __restrict__ out) {
    const int plane = blockIdx.y;
    if (plane < 6) {
        const int n = plane / 3, c = plane % 3;
        const float4* xp = (const float4*)(x + ((size_t)n * 4 + c) * NP);
        float s = 0.0f;
        for (int i = blockIdx.x * 256 + threadIdx.x; i < NP / 4; i += 128 * 256) {
            float4 v = xp[i];
            s += (v.x + v.y) + (v.z + v.w);
        }
        #pragma unroll
        for (int off = 32; off > 0; off >>= 1) s += __shfl_down(s, off, 64);
        __shared__ float wsum[4];
        if ((threadIdx.x & 63) == 0) wsum[threadIdx.x >> 6] = s;
        __syncthreads();
        if (threadIdx.x == 0)
            ws[SUMS_OFF + plane * 128 + blockIdx.x] =
                (wsum[0] + wsum[1]) + (wsum[2] + wsum[3]);
    } else {
        float4* o4 = (float4*)out;
        const float4 z = make_float4(0.f, 0.f, 0.f, 0.f);
        for (int i = blockIdx.x * 256 + threadIdx.x; i < NBATCH * NP / 4; i += 128 * 256)
            o4[i] = z;
    }
}

__device__ __forceinline__ void load_means128(const float* __restrict__ ws, int n,
                                              float& m0, float& m1, float& m2) {
    float s0 = 0.f, s1 = 0.f, s2 = 0.f;
    const float* p0 = ws + SUMS_OFF + (n * 3 + 0) * 128;
    const float* p1 = ws + SUMS_OFF + (n * 3 + 1) * 128;
    const float* p2 = ws + SUMS_OFF + (n * 3 + 2) * 128;
    #pragma unroll 4
    for (int b = 0; b < 128; ++b) { s0 += p0[b]; s1 += p1[b]; s2 += p2[b]; }
    const float inv_np = 1.0f / (float)NP;
    m0 = s0 * inv_np; m1 = s1 * inv_np; m2 = s2 * inv_np;
}

// Packed pair deposit: cells (b, b+1) get (va, vb) in 2^-24 fixed point.
__device__ __forceinline__ void deposit_pair(unsigned long long* __restrict__ winU,
                                             int b, float va, float vb) {
    const int fa = __float2int_rn(va * FXSCALE);
    const int fb = __float2int_rn(vb * FXSCALE);
    const bool odd = (b & 1);
    const long long packed = (((long long)fb) << 32) + (long long)fa;
    const long long hiOnly = ((long long)fa) << 32;
    atomicAdd(&winU[b >> 1], (unsigned long long)(odd ? hiOnly : packed));
    if (odd) atomicAdd(&winU[(b >> 1) + 1], (unsigned long long)(long long)fb);
}

// ---------------------------------------------------------------------------
// Kernel 2: tiled CIC scatter + destination-major flush.
// ---------------------------------------------------------------------------
__global__ __launch_bounds__(NTHR, 4) void scatter_tile_kernel(
        const float* __restrict__ x, const float* __restrict__ ws,
        float* __restrict__ slabs, float* __restrict__ out) {
    const int blk = blockIdx.x;              // 0 .. 2*NTILE-1
    const int n = blk >> 9;
    const int t = blk & (NTILE - 1);
    const int tx = t & 7, ty = (t >> 3) & 7, tz = t >> 6;

    __shared__ ulonglong2 win2[(WINF + 3) / 4 + 1];
    unsigned long long* winU = (unsigned long long*)win2;
    {
        float4* z4 = (float4*)win2;
        const float4 z = make_float4(0.f, 0.f, 0.f, 0.f);
        for (int i = threadIdx.x; i < (WINF + 3) / 4 + 1; i += NTHR) z4[i] = z;
    }
    float m0, m1, m2;
    load_means128(ws, n, m0, m1, m2);
    __syncthreads();

    // ---- deposit phase: 512 threads x 8 particles ----
    const int i0 = threadIdx.x * 8;
    const int lw0 = i0 & 15;
    const int lh  = (i0 >> 4) & 15;
    const int ld  = i0 >> 8;
    const int gd = tz * TS + ld, gh = ty * TS + lh, gw0 = tx * TS + lw0;
    const size_t prow = ((size_t)gd * NDIM + gh) * NDIM + gw0;

    const float4* x4 = (const float4*)(x + (size_t)n * 4 * NP);
    const size_t q = prow >> 2;
    const size_t s4 = NP / 4;
    float4 a0 = x4[0 * s4 + q], a1 = x4[0 * s4 + q + 1];
    float4 b0 = x4[1 * s4 + q], b1 = x4[1 * s4 + q + 1];
    float4 c0 = x4[2 * s4 + q], c1 = x4[2 * s4 + q + 1];
    float4 e0 = x4[3 * s4 + q], e1 = x4[3 * s4 + q + 1];
    const float D0[8] = {a0.x, a0.y, a0.z, a0.w, a1.x, a1.y, a1.z, a1.w};
    const float D1[8] = {b0.x, b0.y, b0.z, b0.w, b1.x, b1.y, b1.z, b1.w};
    const float D2[8] = {c0.x, c0.y, c0.z, c0.w, c1.x, c1.y, c1.z, c1.w};
    const float VV[8] = {e0.x, e0.y, e0.z, e0.w, e1.x, e1.y, e1.z, e1.w};

    const int od = tz * TS - LO, oh = ty * TS - LO, ow = tx * TS - LO;
    float* sp = out + (size_t)n * NP;

    #pragma unroll
    for (int k = 0; k < 8; ++k) {
        const float pd = (D0[k] - m0) * DIS_NORM + (float)gd + 0.5f;
        const float ph = (D1[k] - m1) * DIS_NORM + (float)gh + 0.5f;
        const float pw = (D2[k] - m2) * DIS_NORM + (float)(gw0 + k) + 0.5f;
        const float v = VV[k];

        const float fd = floorf(pd), fh = floorf(ph), fw = floorf(pw);
        const int id = (int)fd, ih = (int)fh, iw = (int)fw;
        const float rd = pd - fd, rh = ph - fh, rw = pw - fw;

        const int wd = id - od, wh = ih - oh, ww = iw - ow;
        if ((unsigned)wd <= WIN - 2 && (unsigned)wh <= WIN - 2 &&
            (unsigned)ww <= WIN - 2) {
            const int b00 = (wd * WIN + wh) * WIN + ww;
            const float sd0 = v * (1.0f - rd), sd1 = v * rd;
            const float h0 = 1.0f - rh, h1 = rh;
            const float q0 = 1.0f - rw, q1 = rw;
            deposit_pair(winU, b00,              sd0 * h0 * q0, sd0 * h0 * q1);
            deposit_pair(winU, b00 + WIN,        sd0 * h1 * q0, sd0 * h1 * q1);
            deposit_pair(winU, b00 + WIN2,       sd1 * h0 * q0, sd1 * h0 * q1);
            deposit_pair(winU, b00 + WIN2 + WIN, sd1 * h1 * q0, sd1 * h1 * q1);
        } else {
            const float wd2[2]  = {1.0f - rd, rd};
            const float wh2[2]  = {1.0f - rh, rh};
            const float ww2[2]  = {1.0f - rw, rw};
            #pragma unroll
            for (int dd = 0; dd < 2; ++dd) {
                const int td = id + dd, wdc = wd + dd;
                const bool dW = (unsigned)wdc < WIN, dM = (unsigned)td < NDIM;
                if (!dM && !dW) continue;
                #pragma unroll
                for (int hh = 0; hh < 2; ++hh) {
                    const int th = ih + hh, whc = wh + hh;
                    const bool hW = (unsigned)whc < WIN, hM = (unsigned)th < NDIM;
                    const float vdh = v * wd2[dd] * wh2[hh];
                    #pragma unroll
                    for (int wi = 0; wi < 2; ++wi) {
                        const int tw = iw + wi, wwc = ww + wi;
                        const bool wW = (unsigned)wwc < WIN, wM = (unsigned)tw < NDIM;
                        const float dep = vdh * ww2[wi];
                        if (dW && hW && wW) {
                            const int cb = (wdc * WIN + whc) * WIN + wwc;
                            const int fx = __float2int_rn(dep * FXSCALE);
                            const long long cv = (cb & 1)
                                ? (((long long)fx) << 32) : (long long)fx;
                            atomicAdd(&winU[cb >> 1], (unsigned long long)cv);
                        } else if (dM && hM && wM) {
                            atomicAdd(sp + ((size_t)td * NDIM + th) * NDIM + tw, dep);
                        }
                    }
                }
            }
        }
    }

    __syncthreads();

    // ---- flush phase: write each window cell into its DEST tile's slab ----
    // piece index po = (oz+1)*9+(oy+1)*3+(ox+1), o = src - dest = -m
    const int EXT[3]  = {6, 16, 5};                       // extent by o+1
    const int BASE[27] = {0,216,792,972,1548,3084,3564,3744,4224,
                          4376,4952,6488,6968,8504,12600,13880,14360,15640,
                          16040,16220,16700,16852,17332,18612,19012,19164,19564};
    const int nbase = n << 9;

    for (int c = threadIdx.x; c < WINF; c += NTHR) {
        const int lz = c / WIN2;
        const int rz = c - lz * WIN2;
        const int ly = rz / WIN;
        const int lx = rz - ly * WIN;

        int mz, pz;
        if (lz < LO) { mz = -1; pz = lz; }
        else if (lz < LO + TS) { mz = 0; pz = lz - LO; }
        else { mz = 1; pz = lz - LO - TS; }
        int my, py;
        if (ly < LO) { my = -1; py = ly; }
        else if (ly < LO + TS) { my = 0; py = ly - LO; }
        else { my = 1; py = ly - LO - TS; }
        int mx, px;
        if (lx < LO) { mx = -1; px = lx; }
        else if (lx < LO + TS) { mx = 0; px = lx - LO; }
        else { mx = 1; px = lx - LO - TS; }

        const int dtz = tz + mz, dty = ty + my, dtx = tx + mx;
        if ((unsigned)dtz >= TPB || (unsigned)dty >= TPB || (unsigned)dtx >= TPB)
            continue;   // out-of-mesh dest: masked (matches reference)

        const int jz = 1 - mz, jy = 1 - my, jx = 1 - mx;
        const int po = jz * 9 + jy * 3 + jx;
        const int linear = (pz * EXT[jy] + py) * EXT[jx] + px;

        const unsigned long long u = winU[c >> 1];
        const int lo = (int)(unsigned)(u & 0xffffffffull);
        const int hi = (int)(u >> 32) + (lo < 0 ? 1 : 0);
        const float val = (float)((c & 1) ? hi : lo) * FXINV;

        slabs[(size_t)(nbase + (dtz * 8 + dty) * 8 + dtx) * SLAB + BASE[po] + linear] = val;
    }
}

// ---------------------------------------------------------------------------
// Kernel 3: gather. Block = one dest tile; reads its own contiguous slab
// (27 pieces), accumulates into a 16^3 LDS tile, float4 RMW against out.
// ---------------------------------------------------------------------------
__global__ __launch_bounds__(NTHR) void gather_tile_kernel(const float* __restrict__ slabs,
                                                           float* __restrict__ out) {
    const int blk = blockIdx.x;              // 0 .. 2*NTILE-1
    const int t = blk & (NTILE - 1);
    const int tx = t & 7, ty = (t >> 3) & 7, tz = t >> 6;

    __shared__ float tile[TS * TS * TS];     // 16 KB
    for (int i = threadIdx.x; i < TS * TS * TS; i += NTHR) tile[i] = 0.0f;
    __syncthreads();

    const float* slab = slabs + (size_t)blk * SLAB;
    const int EXT[3] = {6, 16, 5};           // extent by o+1
    const int DST[3] = {0, 0, 11};           // dest-local start by o+1
    const int BASE[27] = {0,216,792,972,1548,3084,3564,3744,4224,
                          4376,4952,6488,6968,8504,12600,13880,14360,15640,
                          16040,16220,16700,16852,17332,18612,19012,19164,19564};

    #pragma unroll
    for (int sec = 0; sec < 27; ++sec) {
        const int jz = sec / 9, jy = (sec / 3) % 3, jx = sec % 3;
        const int oz = jz - 1, oy = jy - 1, ox = jx - 1;
        // piece exists iff source tile (dest + o) is in range
        if ((unsigned)(tz + oz) < TPB && (unsigned)(ty + oy) < TPB &&
            (unsigned)(tx + ox) < TPB) {
            const int ez = EXT[jz], ey = EXT[jy], ex = EXT[jx];
            const int npc = ez * ey * ex;
            const int sz = DST[jz], sy = DST[jy], sx = DST[jx];
            const float* pc = slab + BASE[sec];
            for (int i = threadIdx.x; i < npc; i += NTHR) {
                const int pz = i / (ey * ex);
                const int r  = i - pz * (ey * ex);
                const int py = r / ex;
                const int px = r - py * ex;
                tile[((sz + pz) * TS + sy + py) * TS + sx + px] += pc[i];
            }
        }
        __syncthreads();
    }

    // epilogue: out = tile + spill (out holds spill deposits)
    const int n = blk >> 9;
    float* ob = out + (size_t)n * NP;
    for (int i4 = threadIdx.x; i4 < TS * TS * TS / 4; i4 += NTHR) {
        const int xq = i4 & 3, y = (i4 >> 2) & 15, z = i4 >> 6;
        float4 v = ((const float4*)tile)[i4];
        const size_t g = (((size_t)(tz * TS + z) * NDIM) + ty * TS + y) * NDIM
                       + tx * TS + xq * 4;
        float4 o = *(const float4*)(ob + g);
        v.x += o.x; v.y += o.y; v.z += o.z; v.w += o.w;
        *(float4*)(ob + g) = v;
    }
}

// ---------------------------------------------------------------------------
// Fallback (small ws): direct device-scope atomic scatter into out
// ---------------------------------------------------------------------------
__global__ __launch_bounds__(256) void scatter_direct_kernel(const float* __restrict__ x,
                                                             const float* __restrict__ ws,
                                                             float* __restrict__ out) {
    const int lin = blockIdx.x * 256 + threadIdx.x;
    const int n = lin >> 21;
    const int p = lin & (NP - 1);

    float m0, m1, m2;
    load_means128(ws, n, m0, m1, m2);

    const size_t base = (size_t)n * 4 * NP;
    const float d0 = x[base + 0 * (size_t)NP + p];
    const float d1 = x[base + 1 * (size_t)NP + p];
    const float d2 = x[base + 2 * (size_t)NP + p];
    const float v  = x[base + 3 * (size_t)NP + p];

    const int w = p & 127, h = (p >> 7) & 127, d = p >> 14;
    const float pd = (d0 - m0) * DIS_NORM + (float)d + 0.5f;
    const float ph = (d1 - m1) * DIS_NORM + (float)h + 0.5f;
    const float pw = (d2 - m2) * DIS_NORM + (float)w + 0.5f;
    const float fd = floorf(pd), fh = floorf(ph), fw = floorf(pw);
    const int id = (int)fd, ih = (int)fh, iw = (int)fw;
    const float rd = pd - fd, rh = ph - fh, rw = pw - fw;
    const float wd[2] = {1.0f - rd, rd}, wh[2] = {1.0f - rh, rh}, ww[2] = {1.0f - rw, rw};
    float* o = out + (size_t)n * NP;
    #pragma unroll
    for (int dd = 0; dd < 2; ++dd) {
        const int td = id + dd;
        if ((unsigned)td >= (unsigned)NDIM) continue;
        #pragma unroll
        for (int hh = 0; hh < 2; ++hh) {
            const int th = ih + hh;
            if ((unsigned)th >= (unsigned)NDIM) continue;
            const float vdh = v * wd[dd] * wh[hh];
            const int rowbase = (td * NDIM + th) * NDIM;
            #pragma unroll
            for (int wi = 0; wi < 2; ++wi) {
                const int tw = iw + wi;
                if ((unsigned)tw >= (unsigned)NDIM) continue;
                atomicAdd(o + rowbase + tw, vdh * ww[wi]);
            }
        }
    }
}

extern "C" void kernel_launch(void* const* d_in, const int* in_sizes, int n_in,
                              void* d_out, int out_size, void* d_ws, size_t ws_size,
                              hipStream_t stream) {
    const float* x = (const float*)d_in[0];
    float* out = (float*)d_out;
    float* ws = (float*)d_ws;
    float* slabs = ws + SLABS_OFF;

    dim3 pgrid(128, 7);   // 6 sum planes + 1 out-zero plane

    if (ws_size >= WS_NEEDED_BYTES) {
        prep_kernel<<<pgrid, 256, 0, stream>>>(x, ws, out);
        scatter_tile_kernel<<<dim3(NBATCH * NTILE), NTHR, 0, stream>>>(x, ws, slabs, out);
        gather_tile_kernel<<<dim3(NBATCH * NTILE), NTHR, 0, stream>>>(slabs, out);
    } else {
        prep_kernel<<<pgrid, 256, 0, stream>>>(x, ws, out);
        scatter_direct_kernel<<<dim3(NBATCH * NP / 256), 256, 0, stream>>>(x, ws, out);
    }
}

// Round 9
// 188.025 us; speedup vs baseline: 1.8033x; 1.1422x over previous
//
#include <hip/hip_runtime.h>

// Problem constants (fixed by reference: x is (2, 4, 128, 128, 128) fp32)
#define NBATCH 2
#define NDIM   128
#define NP     (128 * 128 * 128)        // particles per batch = mesh cells (2^21)
#define DIS_NORM 3.072f                  // 6 * 512 / 1000

// Tiling: 16^3 origin tiles; LDS window halo LO=5 below, HI=6 above.
// WIN=27 -> 19683 cells as PACKED u64 pairs, 2^-24 fixed point, ds_add_u64
// deposits (6 atomics/particle). 78.75 KB LDS -> 2 blocks/CU in scatter.
#define TS   16
#define LO   5
#define HI   6
#define WIN  (TS + LO + HI)              // 27
#define WIN2 (WIN * WIN)                 // 729
#define WINF (WIN * WIN * WIN)           // 19683
#define TPB  8
#define NTILE (TPB * TPB * TPB)          // 512 tiles per batch
#define NTHR 512

#define FXSCALE 16777216.0f              // 2^24
#define FXINV   (1.0f / 16777216.0f)

// Destination-major inbox: each dest tile owns a contiguous slab of 27
// pieces (source offset o = src - dest; extents by j = 1 - m: {6,16,5}),
// piece bases padded to 4 floats. Slab = 19692 -> 19696 floats.
#define SLAB 19696

// ws layout (floats): [0..1024) partial sums; [1024..) per-tile slabs
#define SUMS_OFF 0
#define SLABS_OFF 1024
#define WS_FLOATS ((size_t)SLABS_OFF + (size_t)NBATCH * NTILE * SLAB)
#define WS_NEEDED_BYTES (WS_FLOATS * sizeof(float))

__device__ __constant__ int BASE27[27] = {
    0,216,792,972,1548,3084,3564,3744,4224,
    4376,4952,6488,6968,8504,12600,13880,14360,15640,
    16040,16220,16700,16852,17332,18612,19012,19164,19564};

// ---------------------------------------------------------------------------
// Kernel 1: prep. Planes 0..5: per-block partial sums of displacement
// channels. Plane 6: zero d_out (spill deposits land there atomically).
// ---------------------------------------------------------------------------
__global__ __launch_bounds__(256) void prep_kernel(const float* __restrict__ x,
                                                   float* __restrict__ ws,
                                                   float* __restrict__ out) {
    const int plane = blockIdx.y;
    if (plane < 6) {
        const int n = plane / 3, c = plane % 3;
        const float4* xp = (const float4*)(x + ((size_t)n * 4 + c) * NP);
        float s = 0.0f;
        for (int i = blockIdx.x * 256 + threadIdx.x; i < NP / 4; i += 128 * 256) {
            float4 v = xp[i];
            s += (v.x + v.y) + (v.z + v.w);
        }
        #pragma unroll
        for (int off = 32; off > 0; off >>= 1) s += __shfl_down(s, off, 64);
        __shared__ float wsum[4];
        if ((threadIdx.x & 63) == 0) wsum[threadIdx.x >> 6] = s;
        __syncthreads();
        if (threadIdx.x == 0)
            ws[SUMS_OFF + plane * 128 + blockIdx.x] =
                (wsum[0] + wsum[1]) + (wsum[2] + wsum[3]);
    } else {
        float4* o4 = (float4*)out;
        const float4 z = make_float4(0.f, 0.f, 0.f, 0.f);
        for (int i = blockIdx.x * 256 + threadIdx.x; i < NBATCH * NP / 4; i += 128 * 256)
            o4[i] = z;
    }
}

__device__ __forceinline__ void load_means128(const float* __restrict__ ws, int n,
                                              float& m0, float& m1, float& m2) {
    float s0 = 0.f, s1 = 0.f, s2 = 0.f;
    const float* p0 = ws + SUMS_OFF + (n * 3 + 0) * 128;
    const float* p1 = ws + SUMS_OFF + (n * 3 + 1) * 128;
    const float* p2 = ws + SUMS_OFF + (n * 3 + 2) * 128;
    #pragma unroll 4
    for (int b = 0; b < 128; ++b) { s0 += p0[b]; s1 += p1[b]; s2 += p2[b]; }
    const float inv_np = 1.0f / (float)NP;
    m0 = s0 * inv_np; m1 = s1 * inv_np; m2 = s2 * inv_np;
}

// Packed pair deposit: cells (b, b+1) get (va, vb) in 2^-24 fixed point.
__device__ __forceinline__ void deposit_pair(unsigned long long* __restrict__ winU,
                                             int b, float va, float vb) {
    const int fa = __float2int_rn(va * FXSCALE);
    const int fb = __float2int_rn(vb * FXSCALE);
    const bool odd = (b & 1);
    const long long packed = (((long long)fb) << 32) + (long long)fa;
    const long long hiOnly = ((long long)fa) << 32;
    atomicAdd(&winU[b >> 1], (unsigned long long)(odd ? hiOnly : packed));
    if (odd) atomicAdd(&winU[(b >> 1) + 1], (unsigned long long)(long long)fb);
}

// ---------------------------------------------------------------------------
// Kernel 2: tiled CIC scatter + cheap destination-major flush.
// ---------------------------------------------------------------------------
__global__ __launch_bounds__(NTHR, 4) void scatter_tile_kernel(
        const float* __restrict__ x, const float* __restrict__ ws,
        float* __restrict__ slabs, float* __restrict__ out) {
    const int blk = blockIdx.x;              // 0 .. 2*NTILE-1
    const int n = blk >> 9;
    const int t = blk & (NTILE - 1);
    const int tx = t & 7, ty = (t >> 3) & 7, tz = t >> 6;

    __shared__ ulonglong2 win2[(WINF + 3) / 4 + 1];   // 78752 B
    unsigned long long* winU = (unsigned long long*)win2;
    {
        float4* z4 = (float4*)win2;
        const float4 z = make_float4(0.f, 0.f, 0.f, 0.f);
        for (int i = threadIdx.x; i < (WINF + 3) / 4 + 1; i += NTHR) z4[i] = z;
    }
    float m0, m1, m2;
    load_means128(ws, n, m0, m1, m2);
    __syncthreads();

    // ---- deposit phase: 512 threads x 8 particles ----
    const int i0 = threadIdx.x * 8;
    const int lw0 = i0 & 15;
    const int lh  = (i0 >> 4) & 15;
    const int ld  = i0 >> 8;
    const int gd = tz * TS + ld, gh = ty * TS + lh, gw0 = tx * TS + lw0;
    const size_t prow = ((size_t)gd * NDIM + gh) * NDIM + gw0;

    const float4* x4 = (const float4*)(x + (size_t)n * 4 * NP);
    const size_t q = prow >> 2;
    const size_t s4 = NP / 4;
    float4 a0 = x4[0 * s4 + q], a1 = x4[0 * s4 + q + 1];
    float4 b0 = x4[1 * s4 + q], b1 = x4[1 * s4 + q + 1];
    float4 c0 = x4[2 * s4 + q], c1 = x4[2 * s4 + q + 1];
    float4 e0 = x4[3 * s4 + q], e1 = x4[3 * s4 + q + 1];
    const float D0[8] = {a0.x, a0.y, a0.z, a0.w, a1.x, a1.y, a1.z, a1.w};
    const float D1[8] = {b0.x, b0.y, b0.z, b0.w, b1.x, b1.y, b1.z, b1.w};
    const float D2[8] = {c0.x, c0.y, c0.z, c0.w, c1.x, c1.y, c1.z, c1.w};
    const float VV[8] = {e0.x, e0.y, e0.z, e0.w, e1.x, e1.y, e1.z, e1.w};

    const int od = tz * TS - LO, oh = ty * TS - LO, ow = tx * TS - LO;
    float* sp = out + (size_t)n * NP;

    #pragma unroll
    for (int k = 0; k < 8; ++k) {
        const float pd = (D0[k] - m0) * DIS_NORM + (float)gd + 0.5f;
        const float ph = (D1[k] - m1) * DIS_NORM + (float)gh + 0.5f;
        const float pw = (D2[k] - m2) * DIS_NORM + (float)(gw0 + k) + 0.5f;
        const float v = VV[k];

        const float fd = floorf(pd), fh = floorf(ph), fw = floorf(pw);
        const int id = (int)fd, ih = (int)fh, iw = (int)fw;
        const float rd = pd - fd, rh = ph - fh, rw = pw - fw;

        const int wd = id - od, wh = ih - oh, ww = iw - ow;
        if ((unsigned)wd <= WIN - 2 && (unsigned)wh <= WIN - 2 &&
            (unsigned)ww <= WIN - 2) {
            const int b00 = (wd * WIN + wh) * WIN + ww;
            const float sd0 = v * (1.0f - rd), sd1 = v * rd;
            const float h0 = 1.0f - rh, h1 = rh;
            const float q0 = 1.0f - rw, q1 = rw;
            deposit_pair(winU, b00,              sd0 * h0 * q0, sd0 * h0 * q1);
            deposit_pair(winU, b00 + WIN,        sd0 * h1 * q0, sd0 * h1 * q1);
            deposit_pair(winU, b00 + WIN2,       sd1 * h0 * q0, sd1 * h0 * q1);
            deposit_pair(winU, b00 + WIN2 + WIN, sd1 * h1 * q0, sd1 * h1 * q1);
        } else {
            const float wd2[2]  = {1.0f - rd, rd};
            const float wh2[2]  = {1.0f - rh, rh};
            const float ww2[2]  = {1.0f - rw, rw};
            #pragma unroll
            for (int dd = 0; dd < 2; ++dd) {
                const int td = id + dd, wdc = wd + dd;
                const bool dW = (unsigned)wdc < WIN, dM = (unsigned)td < NDIM;
                if (!dM && !dW) continue;
                #pragma unroll
                for (int hh = 0; hh < 2; ++hh) {
                    const int th = ih + hh, whc = wh + hh;
                    const bool hW = (unsigned)whc < WIN, hM = (unsigned)th < NDIM;
                    const float vdh = v * wd2[dd] * wh2[hh];
                    #pragma unroll
                    for (int wi = 0; wi < 2; ++wi) {
                        const int tw = iw + wi, wwc = ww + wi;
                        const bool wW = (unsigned)wwc < WIN, wM = (unsigned)tw < NDIM;
                        const float dep = vdh * ww2[wi];
                        if (dW && hW && wW) {
                            const int cb = (wdc * WIN + whc) * WIN + wwc;
                            const int fx = __float2int_rn(dep * FXSCALE);
                            const long long cv = (cb & 1)
                                ? (((long long)fx) << 32) : (long long)fx;
                            atomicAdd(&winU[cb >> 1], (unsigned long long)cv);
                        } else if (dM && hM && wM) {
                            atomicAdd(sp + ((size_t)td * NDIM + th) * NDIM + tw, dep);
                        }
                    }
                }
            }
        }
    }

    __syncthreads();

    // ---- decode pass: in-place u64 fixed-point -> 2x fp32 (no races) ----
    {
        const int NU = (WINF + 1) / 2;   // 9842
        for (int i = threadIdx.x; i < NU; i += NTHR) {
            const unsigned long long u = winU[i];
            const int lo = (int)(unsigned)(u & 0xffffffffull);
            const int hi = (int)(u >> 32) + (lo < 0 ? 1 : 0);
            float2 f;
            f.x = (float)lo * FXINV;
            f.y = (float)hi * FXINV;
            ((float2*)winU)[i] = f;
        }
    }
    __syncthreads();
    const float* winF = (const float*)winU;

    // ---- flush: one thread per (lz,ly) row; 3 fixed x-segments ----
    const int EXTY[3] = {6, 16, 5};
    const int nbase = n << 9;
    for (int r = threadIdx.x; r < WIN2; r += NTHR) {
        const int lz = r / WIN;
        const int ly = r - lz * WIN;
        int mz, pz;
        if (lz < LO) { mz = -1; pz = lz; }
        else if (lz < LO + TS) { mz = 0; pz = lz - LO; }
        else { mz = 1; pz = lz - LO - TS; }
        int my, py;
        if (ly < LO) { my = -1; py = ly; }
        else if (ly < LO + TS) { my = 0; py = ly - LO; }
        else { my = 1; py = ly - LO - TS; }
        const int dtz = tz + mz, dty = ty + my;
        if ((unsigned)dtz >= TPB || (unsigned)dty >= TPB) continue;

        const int jz = 1 - mz, jy = 1 - my;
        const int ey = EXTY[jy];
        const int rowoff = pz * ey + py;
        const int pobase = jz * 9 + jy * 3;
        const float* src = winF + r * WIN;
        const int slabRow = nbase + (dtz * 8 + dty) * 8;

        // seg A: jx=2 (dest tile tx-1), lx 0..4, ex=5
        if (tx > 0) {
            float* d = slabs + (size_t)(slabRow + tx - 1) * SLAB
                     + BASE27[pobase + 2] + rowoff * 5;
            #pragma unroll
            for (int k = 0; k < 5; ++k) d[k] = src[k];
        }
        // seg B: jx=1 (own tile), lx 5..20, ex=16, aligned float4 stores
        {
            float* d = slabs + (size_t)(slabRow + tx) * SLAB
                     + BASE27[pobase + 1] + rowoff * 16;
            #pragma unroll
            for (int k = 0; k < 4; ++k) {
                float4 v;
                v.x = src[5 + 4 * k]; v.y = src[6 + 4 * k];
                v.z = src[7 + 4 * k]; v.w = src[8 + 4 * k];
                ((float4*)d)[k] = v;
            }
        }
        // seg C: jx=0 (dest tile tx+1), lx 21..26, ex=6
        if (tx < TPB - 1) {
            float* d = slabs + (size_t)(slabRow + tx + 1) * SLAB
                     + BASE27[pobase + 0] + rowoff * 6;
            #pragma unroll
            for (int k = 0; k < 6; ++k) d[k] = src[21 + k];
        }
    }
}

// ---------------------------------------------------------------------------
// Kernel 3: gather. Block = one dest tile; reads its own contiguous slab
// (27 pieces), accumulates into a 16^3 LDS tile, float4 RMW against out.
// ---------------------------------------------------------------------------
__global__ __launch_bounds__(NTHR) void gather_tile_kernel(const float* __restrict__ slabs,
                                                           float* __restrict__ out) {
    const int blk = blockIdx.x;              // 0 .. 2*NTILE-1
    const int t = blk & (NTILE - 1);
    const int tx = t & 7, ty = (t >> 3) & 7, tz = t >> 6;

    __shared__ float tile[TS * TS * TS];     // 16 KB
    for (int i = threadIdx.x; i < TS * TS * TS; i += NTHR) tile[i] = 0.0f;
    __syncthreads();

    const float* slab = slabs + (size_t)blk * SLAB;
    const int EXT[3] = {6, 16, 5};           // extent by j
    const int DST[3] = {0, 0, 11};           // dest-local start by j

    #pragma unroll
    for (int sec = 0; sec < 27; ++sec) {
        const int jz = sec / 9, jy = (sec / 3) % 3, jx = sec % 3;
        const int oz = jz - 1, oy = jy - 1, ox = jx - 1;
        if ((unsigned)(tz + oz) < TPB && (unsigned)(ty + oy) < TPB &&
            (unsigned)(tx + ox) < TPB) {
            const int ez = EXT[jz], ey = EXT[jy], ex = EXT[jx];
            const int sz = DST[jz], sy = DST[jy], sx = DST[jx];
            const float* pc = slab + BASE27[sec];
            if (jx == 1) {
                // ex==16: float4 piece loads + float4 LDS tile RMW
                const int nq = ez * ey * 4;          // float4s in piece
                for (int i4 = threadIdx.x; i4 < nq; i4 += NTHR) {
                    const int row = i4 >> 2, qd = i4 & 3;
                    const int pz = row / ey, py = row - pz * ey;
                    float4 v = ((const float4*)pc)[i4];
                    float4* tp = (float4*)&tile[((sz + pz) * TS + sy + py) * TS + qd * 4];
                    float4 o = *tp;
                    o.x += v.x; o.y += v.y; o.z += v.z; o.w += v.w;
                    *tp = o;
                }
            } else {
                const int npc = ez * ey * ex;
                for (int i = threadIdx.x; i < npc; i += NTHR) {
                    const int pz = i / (ey * ex);
                    const int r  = i - pz * (ey * ex);
                    const int py = r / ex;
                    const int px = r - py * ex;
                    tile[((sz + pz) * TS + sy + py) * TS + sx + px] += pc[i];
                }
            }
        }
        __syncthreads();
    }

    // epilogue: out = tile + spill (out holds spill deposits)
    const int n = blk >> 9;
    float* ob = out + (size_t)n * NP;
    for (int i4 = threadIdx.x; i4 < TS * TS * TS / 4; i4 += NTHR) {
        const int xq = i4 & 3, y = (i4 >> 2) & 15, z = i4 >> 6;
        float4 v = ((const float4*)tile)[i4];
        const size_t g = (((size_t)(tz * TS + z) * NDIM) + ty * TS + y) * NDIM
                       + tx * TS + xq * 4;
        float4 o = *(const float4*)(ob + g);
        v.x += o.x; v.y += o.y; v.z += o.z; v.w += o.w;
        *(float4*)(ob + g) = v;
    }
}

// ---------------------------------------------------------------------------
// Fallback (small ws): direct device-scope atomic scatter into out
// ---------------------------------------------------------------------------
__global__ __launch_bounds__(256) void scatter_direct_kernel(const float* __restrict__ x,
                                                             const float* __restrict__ ws,
                                                             float* __restrict__ out) {
    const int lin = blockIdx.x * 256 + threadIdx.x;
    const int n = lin >> 21;
    const int p = lin & (NP - 1);

    float m0, m1, m2;
    load_means128(ws, n, m0, m1, m2);

    const size_t base = (size_t)n * 4 * NP;
    const float d0 = x[base + 0 * (size_t)NP + p];
    const float d1 = x[base + 1 * (size_t)NP + p];
    const float d2 = x[base + 2 * (size_t)NP + p];
    const float v  = x[base + 3 * (size_t)NP + p];

    const int w = p & 127, h = (p >> 7) & 127, d = p >> 14;
    const float pd = (d0 - m0) * DIS_NORM + (float)d + 0.5f;
    const float ph = (d1 - m1) * DIS_NORM + (float)h + 0.5f;
    const float pw = (d2 - m2) * DIS_NORM + (float)w + 0.5f;
    const float fd = floorf(pd), fh = floorf(ph), fw = floorf(pw);
    const int id = (int)fd, ih = (int)fh, iw = (int)fw;
    const float rd = pd - fd, rh = ph - fh, rw = pw - fw;
    const float wd[2] = {1.0f - rd, rd}, wh[2] = {1.0f - rh, rh}, ww[2] = {1.0f - rw, rw};
    float* o = out + (size_t)n * NP;
    #pragma unroll
    for (int dd = 0; dd < 2; ++dd) {
        const int td = id + dd;
        if ((unsigned)td >= (unsigned)NDIM) continue;
        #pragma unroll
        for (int hh = 0; hh < 2; ++hh) {
            const int th = ih + hh;
            if ((unsigned)th >= (unsigned)NDIM) continue;
            const float vdh = v * wd[dd] * wh[hh];
            const int rowbase = (td * NDIM + th) * NDIM;
            #pragma unroll
            for (int wi = 0; wi < 2; ++wi) {
                const int tw = iw + wi;
                if ((unsigned)tw >= (unsigned)NDIM) continue;
                atomicAdd(o + rowbase + tw, vdh * ww[wi]);
            }
        }
    }
}

extern "C" void kernel_launch(void* const* d_in, const int* in_sizes, int n_in,
                              void* d_out, int out_size, void* d_ws, size_t ws_size,
                              hipStream_t stream) {
    const float* x = (const float*)d_in[0];
    float* out = (float*)d_out;
    float* ws = (float*)d_ws;
    float* slabs = ws + SLABS_OFF;

    dim3 pgrid(128, 7);   // 6 sum planes + 1 out-zero plane

    if (ws_size >= WS_NEEDED_BYTES) {
        prep_kernel<<<pgrid, 256, 0, stream>>>(x, ws, out);
        scatter_tile_kernel<<<dim3(NBATCH * NTILE), NTHR, 0, stream>>>(x, ws, slabs, out);
        gather_tile_kernel<<<dim3(NBATCH * NTILE), NTHR, 0, stream>>>(slabs, out);
    } else {
        prep_kernel<<<pgrid, 256, 0, stream>>>(x, ws, out);
        scatter_direct_kernel<<<dim3(NBATCH * NP / 256), 256, 0, stream>>>(x, ws, out);
    }
}